// Round 1
// baseline (141.635 us; speedup 1.0000x reference)
//
#include <hip/hip_runtime.h>
#include <cstdint>
#include <cstddef>

#define BATCH  8192
#define DIM    256
#define NSTRIP 8
#define SCOLS  1024           // columns per strip
#define MROWS  128            // rows per block (4 waves x 32 rows)
#define NTILE  64             // cols per inner iteration
#define NITER  (SCOLS/NTILE)  // 16

static constexpr float INV_T   = 1.0f / 0.07f;
static constexpr float EXP2_SC = 1.4426950408889634f / 0.07f;  // log2(e)/T
static constexpr float MARGIN  = 0.2f;

typedef __attribute__((ext_vector_type(8))) short short8;
typedef __attribute__((ext_vector_type(4))) float f32x4;

__device__ __forceinline__ unsigned short f2bf(float f){
  unsigned int u = __float_as_uint(f);
  u += 0x7FFFu + ((u >> 16) & 1u);     // round-to-nearest-even
  return (unsigned short)(u >> 16);
}

__device__ __forceinline__ void ins3(float& t0, float& t1, float& t2, float s){
  float m0 = fmaxf(t0, s); float r1 = fminf(t0, s); t0 = m0;
  float m1 = fmaxf(t1, r1); float r2 = fminf(t1, r1); t1 = m1;
  t2 = fmaxf(t2, r2);
}

// ---- kernel 1: L2-normalize rows (fp32), cast to bf16; zero scalar accumulators
__global__ void norm_cast_kernel(const float* __restrict__ emb,
                                 unsigned short* __restrict__ E,
                                 float* __restrict__ accum){
  if (blockIdx.x == 0 && threadIdx.x < 8) accum[threadIdx.x] = 0.0f;
  const int wave = threadIdx.x >> 6;
  const int lane = threadIdx.x & 63;
  const int row  = blockIdx.x * 4 + wave;
  const float4 v = *(const float4*)(emb + (size_t)row * DIM + lane * 4);
  float ss = v.x*v.x + v.y*v.y + v.z*v.z + v.w*v.w;
  #pragma unroll
  for (int m = 1; m < 64; m <<= 1) ss += __shfl_xor(ss, m, 64);
  float nrm = fmaxf(sqrtf(ss), 1e-12f);
  float inv = 1.0f / nrm;
  ushort4 o;
  o.x = f2bf(v.x * inv); o.y = f2bf(v.y * inv);
  o.z = f2bf(v.z * inv); o.w = f2bf(v.w * inv);
  *(ushort4*)(E + (size_t)row * DIM + lane * 4) = o;
}

// ---- kernel 2: fused sim-tile GEMM (bf16 MFMA) + online per-row statistics.
// Grid (NSTRIP, BATCH/MROWS); block 256 = 4 waves; wave w owns rows rb+32w..+32.
// Per-lane partial stats over its column congruence class; strip partials to ws.
__global__ __launch_bounds__(256, 2)
void sim_stats_kernel(const unsigned short* __restrict__ E,
                      const int* __restrict__ labels,
                      float* __restrict__ partials){
  const int strip = blockIdx.x;
  const int rb    = blockIdx.y * MROWS;
  const int cs    = strip * SCOLS;
  const int tid   = threadIdx.x;
  const int wave  = tid >> 6;
  const int lane  = tid & 63;
  const int l     = lane & 15;   // column within 16-wide subtile / A-row
  const int q     = lane >> 4;   // quad: selects k-group and C row group

  // B staging, reordered: [chunk c=(kk*4+q)][row r 0..63] of 8 bf16 (16B).
  // Fragment read addr = ((kk*4+q)*64 + t*16 + l)*16B -> banks 4l%32: 2-way only.
  __shared__ short8 Bs[32 * 64];   // 32 KiB
  __shared__ int labs[SCOLS];      // 4 KiB

  for (int i = tid; i < SCOLS; i += 256) labs[i] = labels[cs + i];

  const int row0 = rb + wave * 32;

  // A fragments for the wave's 32 rows, full K=256, kept in registers.
  short8 a[2][8];
  #pragma unroll
  for (int rt = 0; rt < 2; ++rt){
    const unsigned short* rp = E + (size_t)(row0 + rt*16 + l) * DIM + q * 8;
    #pragma unroll
    for (int kk = 0; kk < 8; ++kk)
      a[rt][kk] = *(const short8*)(rp + kk * 32);
  }

  int labr[2][4];
  #pragma unroll
  for (int rt = 0; rt < 2; ++rt)
    #pragma unroll
    for (int rr = 0; rr < 4; ++rr)
      labr[rt][rr] = labels[row0 + rt*16 + q*4 + rr];

  float all_s[8], pos_s[8], pos_m[8], t0[8], t1[8], t2[8];
  #pragma unroll
  for (int s = 0; s < 8; ++s){
    all_s[s] = 0.f; pos_s[s] = 0.f;
    pos_m[s] = -INFINITY; t0[s] = -INFINITY; t1[s] = -INFINITY; t2[s] = -INFINITY;
  }

  for (int it = 0; it < NITER; ++it){
    const int cb = cs + it * NTILE;
    __syncthreads();  // Bs consumed by everyone before restage
    // async stage: wave handles chunks c = wave*8..+7; lane gathers row cb+lane
    #pragma unroll
    for (int ci = 0; ci < 8; ++ci){
      const int c = wave * 8 + ci;
      const unsigned short* g = E + (size_t)(cb + lane) * DIM + c * 8;
      __builtin_amdgcn_global_load_lds(
        (const __attribute__((address_space(1))) unsigned int*)g,
        (__attribute__((address_space(3))) unsigned int*)&Bs[c * 64],
        16, 0, 0);
    }
    __syncthreads();  // drains vmcnt: Bs ready

    #pragma unroll
    for (int t = 0; t < 4; ++t){
      const int gcol = cb + t * 16 + l;
      const int labc = labs[it * NTILE + t * 16 + l];
      f32x4 acc0 = {0.f,0.f,0.f,0.f};
      f32x4 acc1 = {0.f,0.f,0.f,0.f};
      #pragma unroll
      for (int kk = 0; kk < 8; ++kk){
        short8 b = Bs[(kk * 4 + q) * 64 + t * 16 + l];
        acc0 = __builtin_amdgcn_mfma_f32_16x16x32_bf16(a[0][kk], b, acc0, 0, 0, 0);
        acc1 = __builtin_amdgcn_mfma_f32_16x16x32_bf16(a[1][kk], b, acc1, 0, 0, 0);
      }
      #pragma unroll
      for (int rt = 0; rt < 2; ++rt){
        #pragma unroll
        for (int rr = 0; rr < 4; ++rr){
          const float d    = rt ? acc1[rr] : acc0[rr];
          const int   s    = rt * 4 + rr;
          const int   grow = row0 + rt * 16 + q * 4 + rr;
          const float sim  = d * INV_T;
          const float ex   = __builtin_amdgcn_exp2f(d * EXP2_SC);
          const bool same  = (labc == labr[rt][rr]);
          const bool self  = (gcol == grow);
          all_s[s] += self ? 0.f : ex;
          const bool ispos = same && !self;
          pos_s[s] += ispos ? ex : 0.f;
          pos_m[s]  = fmaxf(pos_m[s], ispos ? sim : -INFINITY);
          const float sn = same ? -INFINITY : sim;
          ins3(t0[s], t1[s], t2[s], sn);
        }
      }
    }
  }

  // butterfly reduce over the 16 column-classes (disjoint-set merge: exact)
  #pragma unroll
  for (int mask = 1; mask < 16; mask <<= 1){
    #pragma unroll
    for (int s = 0; s < 8; ++s){
      all_s[s] += __shfl_xor(all_s[s], mask, 64);
      pos_s[s] += __shfl_xor(pos_s[s], mask, 64);
      pos_m[s]  = fmaxf(pos_m[s], __shfl_xor(pos_m[s], mask, 64));
      float b0 = __shfl_xor(t0[s], mask, 64);
      float b1 = __shfl_xor(t1[s], mask, 64);
      float b2 = __shfl_xor(t2[s], mask, 64);
      ins3(t0[s], t1[s], t2[s], b0);
      ins3(t0[s], t1[s], t2[s], b1);
      ins3(t0[s], t1[s], t2[s], b2);
    }
  }

  if (l == 0){
    #pragma unroll
    for (int s = 0; s < 8; ++s){
      const int grow = row0 + (s >> 2) * 16 + q * 4 + (s & 3);
      float* p = partials + ((size_t)grow * NSTRIP + strip) * 6;
      p[0] = all_s[s]; p[1] = pos_s[s]; p[2] = pos_m[s];
      p[3] = t0[s];    p[4] = t1[s];    p[5] = t2[s];
    }
  }
}

// ---- kernel 3: merge strips per row, compute per-row losses, reduce to scalars
__global__ void merge_kernel(const float* __restrict__ partials,
                             float* __restrict__ accum){
  const int row = blockIdx.x * 256 + threadIdx.x;
  float all_s = 0.f, pos_s = 0.f, pos_m = -INFINITY;
  float t0 = -INFINITY, t1 = -INFINITY, t2 = -INFINITY;
  #pragma unroll
  for (int s = 0; s < NSTRIP; ++s){
    const float* p = partials + ((size_t)row * NSTRIP + s) * 6;
    all_s += p[0]; pos_s += p[1];
    pos_m = fmaxf(pos_m, p[2]);
    ins3(t0, t1, t2, p[3]); ins3(t0, t1, t2, p[4]); ins3(t0, t1, t2, p[5]);
  }
  const bool has_pos = pos_m > -INFINITY;
  float vb = 0.f, vh = 0.f, vhp = 0.f, vm = 0.f, vv = 0.f;
  if (has_pos){
    vhp = 1.f;
    vb  = -logf(pos_s / (all_s + 1e-10f) + 1e-10f);
    const float hnm = (t0 + t1 + t2) * (1.f/3.f);
    vh  = fmaxf(hnm - pos_m + MARGIN, 0.f);     // relu; -inf -> 0
    if (t0 > -INFINITY){
      vv = 1.f;
      vm = fmaxf(t0 - pos_m + MARGIN, 0.f);
    }
  }
  float vals[5] = {vb, vh, vhp, vm, vv};
  #pragma unroll
  for (int m = 1; m < 64; m <<= 1)
    #pragma unroll
    for (int i = 0; i < 5; ++i) vals[i] += __shfl_xor(vals[i], m, 64);
  if ((threadIdx.x & 63) == 0){
    #pragma unroll
    for (int i = 0; i < 5; ++i) atomicAdd(&accum[i], vals[i]);
  }
}

// ---- kernel 4: final scalar combine
__global__ void final_kernel(const float* __restrict__ accum,
                             float* __restrict__ out){
  if (threadIdx.x == 0){
    const float nhp   = fmaxf(accum[2], 1.f);
    const float basic = accum[0] / nhp;
    const float hard  = accum[1] / nhp;
    const float marg  = (accum[4] > 0.f) ? (accum[3] / fmaxf(accum[4], 1.f)) : 0.f;
    out[0] = basic + 0.5f * hard + 0.1f * marg;
  }
}

extern "C" void kernel_launch(void* const* d_in, const int* in_sizes, int n_in,
                              void* d_out, int out_size, void* d_ws, size_t ws_size,
                              hipStream_t stream){
  const float* emb  = (const float*)d_in[0];
  const int* labels = (const int*)d_in[1];
  float* out        = (float*)d_out;
  char* ws          = (char*)d_ws;

  unsigned short* E = (unsigned short*)ws;                              // 4 MiB bf16
  const size_t E_BYTES = (size_t)BATCH * DIM * 2;
  float* partials   = (float*)(ws + E_BYTES);                           // 1.5 MiB
  const size_t P_BYTES = (size_t)BATCH * NSTRIP * 6 * sizeof(float);
  float* accum      = (float*)(ws + E_BYTES + P_BYTES);                 // 8 floats

  norm_cast_kernel<<<BATCH/4, 256, 0, stream>>>(emb, E, accum);
  sim_stats_kernel<<<dim3(NSTRIP, BATCH/MROWS), 256, 0, stream>>>(E, labels, partials);
  merge_kernel<<<BATCH/256, 256, 0, stream>>>(partials, accum);
  final_kernel<<<1, 64, 0, stream>>>(accum, out);
}